// Round 6
// baseline (413.680 us; speedup 1.0000x reference)
//
#include <hip/hip_runtime.h>
#include <math.h>

// Problem constants
#define TT 32
#define BB 16
#define DD 128
#define MAT 16384            // D*D
// Workspace float offsets
#define OFF_MR   0
#define OFF_MI   16384
#define OFF_ZSR  (2129920)                // Zs = Z^T, [kk*16+b][i][j]
#define OFF_ZSI  (OFF_ZSR + 32*16384)
#define OFF_VR   (OFF_ZSI + 32*16384)     // V natural [t*16+b][i][j]
#define OFF_VI   (OFF_VR + 32*16384)
#define OFF_TR   (OFF_VI + 32*16384)      // tr[q][kk][b][2]
#define OFF_S    (OFF_TR + 2048)          // s[q][kk][b]

__device__ __forceinline__ float dot4(float4 a, float4 b) {
    return a.x*b.x + a.y*b.y + a.z*b.z + a.w*b.w;
}

// ---------------- Kernel 1: M = Uq^H * Uk  (complex 128x128) ----------------
__global__ __launch_bounds__(128) void k_M(const float* __restrict__ Uq,
                                           const float* __restrict__ Uk,
                                           float* __restrict__ ws) {
    const int i = blockIdx.x;
    const int j = threadIdx.x;
    __shared__ float qr_s[128], qi_s[128];
    qr_s[j] = Uq[(j*128 + i)*2 + 0];   // Uq[p=j, i]
    qi_s[j] = Uq[(j*128 + i)*2 + 1];
    __syncthreads();
    const float2* Uk2 = (const float2*)Uk;
    float mr = 0.f, mi = 0.f;
    #pragma unroll 8
    for (int p = 0; p < 128; ++p) {
        float2 k2 = Uk2[p*128 + j];
        float qr = qr_s[p], qi = qi_s[p];
        mr += qr*k2.x + qi*k2.y;       // conj(Uq[p,i]) * Uk[p,j]
        mi += qr*k2.y - qi*k2.x;
    }
    ws[OFF_MR + i*128 + j] = mr;
    ws[OFF_MI + i*128 + j] = mi;
}

// ---------------- Kernel 2: fused two-sided evolve Z = U X U^H (v2) ----------------
// grid 512: m = bid&63 (all strips of m + its V twin share XCD m%8),
//           strip i0 = (bid>>6)*16. 256 threads.
// LDS diet: single streamed-B buffer (prefetch held in regs across barrier)
//   => 33280 B/block => 4 blocks/CU (16 waves/CU) for latency hiding.
// Thread: rg = tid&7 (row pair), cg = tid>>3 (col quad).
// Phase 1: Y[i,c] = sum_p U[i,p] X[p,c]   (U = M if m<32 else Uv; X = X[m&31])
// Interlude: Y-strip -> At region as Yt[c][rg]={yr0,yi0,yr1,yi1}.
// Phase 2: Z[i,j] = sum_k Y[i,k] conj(U[j,k])
// Epilogue: m<32 -> store Z^T to Zs (LDS transpose); m>=32 -> store Z to V.
__global__ __launch_bounds__(256, 4) void k_fused(const float* __restrict__ xr,
                                                  const float* __restrict__ xi,
                                                  const float* __restrict__ Uv,
                                                  float* __restrict__ ws) {
    const int bid = blockIdx.x;
    const int m   = bid & 63;            // matrix family
    const int i0  = (bid >> 6) * 16;     // row strip
    const int tid = threadIdx.x;
    const int rg  = tid & 7;             // row pair: rows i0 + rg*2 + {0,1}
    const int cg  = tid >> 3;            // col quad: cols cg*4 + {0..3}

    // LDS: At 4096 f (16KB) | single B buf 4224 f (16.9KB) => 33280 B
    __shared__ __align__(16) float smem_f[4096 + 4224];
    float* At   = smem_f;
    float* Bbuf = smem_f + 4096;

    float accr[2][4], acci[2][4];
    #pragma unroll
    for (int r = 0; r < 2; ++r)
        #pragma unroll
        for (int k = 0; k < 4; ++k) { accr[r][k] = 0.f; acci[r][k] = 0.f; }

    const float2* Uv2 = (const float2*)Uv;
    const float4* Xr4 = (const float4*)(xr + (m & 31) * MAT);
    const float4* Xi4 = (const float4*)(xi + (m & 31) * MAT);

    // ---- Phase-1 A: U strip rows i0..i0+15, interleaved At[p][rg]={r0,i0,r1,i1} ----
    {
        #pragma unroll
        for (int w = 0; w < 4; ++w) {
            int slot = w*256 + tid;          // 0..1023
            int r8 = slot & 7;
            int p  = slot >> 3;              // 0..127
            float ar0, ai0, ar1, ai1;
            if (m < 32) {
                ar0 = ws[OFF_MR + (i0 + r8*2    )*128 + p];
                ai0 = ws[OFF_MI + (i0 + r8*2    )*128 + p];
                ar1 = ws[OFF_MR + (i0 + r8*2 + 1)*128 + p];
                ai1 = ws[OFF_MI + (i0 + r8*2 + 1)*128 + p];
            } else {
                float2 u0 = Uv2[(i0 + r8*2    )*128 + p];
                float2 u1 = Uv2[(i0 + r8*2 + 1)*128 + p];
                ar0 = u0.x; ai0 = u0.y; ar1 = u1.x; ai1 = u1.y;
            }
            *(float4*)&At[p*32 + r8*4] = make_float4(ar0, ai0, ar1, ai1);
        }
    }

    // ---- Phase-1 B staging: X tile t = rows t*16..t*16+15 (regs -> LDS) ----
    float4 pr0, pr1, pi0, pi1;
    auto gloadX = [&](int t) {
        int b0 = t*512;
        pr0 = Xr4[b0 + tid];
        pr1 = Xr4[b0 + 256 + tid];
        pi0 = Xi4[b0 + tid];
        pi1 = Xi4[b0 + 256 + tid];
    };
    auto writeX = [&]() {
        float4* dR = (float4*)(Bbuf);
        float4* dI = (float4*)(Bbuf + 2048);
        dR[tid]       = pr0;
        dR[tid + 256] = pr1;
        dI[tid]       = pi0;
        dI[tid + 256] = pi1;
    };

    gloadX(0);
    writeX();
    __syncthreads();

    // ================= Phase 1 =================
    for (int t = 0; t < 8; ++t) {
        if (t < 7) gloadX(t+1);          // prefetch next tile into regs
        const float* bufR = Bbuf;
        const float* bufI = Bbuf + 2048;
        #pragma unroll
        for (int pp = 0; pp < 16; ++pp) {
            const int p = (t<<4) + pp;
            const float4 a4  = *(const float4*)&At[p*32 + (rg<<2)];
            const float4 brv = *(const float4*)&bufR[pp*128 + (cg<<2)];
            const float4 biv = *(const float4*)&bufI[pp*128 + (cg<<2)];
            const float br_[4] = {brv.x, brv.y, brv.z, brv.w};
            const float bi_[4] = {biv.x, biv.y, biv.z, biv.w};
            #pragma unroll
            for (int k = 0; k < 4; ++k) {
                accr[0][k] += a4.x*br_[k] - a4.y*bi_[k];
                acci[0][k] += a4.x*bi_[k] + a4.y*br_[k];
                accr[1][k] += a4.z*br_[k] - a4.w*bi_[k];
                acci[1][k] += a4.z*bi_[k] + a4.w*br_[k];
            }
        }
        __syncthreads();                  // reads of buf done
        if (t < 7) { writeX(); __syncthreads(); }
    }

    // ================= Interlude =================
    // Phase-2 B prefetch first (hide VMEM under LDS work)
    float2 st[8];
    const int jj = tid >> 4;             // 0..15
    const int kk = tid & 15;             // 0..15
    auto gloadU = [&](int t) {
        int k0 = t*16;
        if (m < 32) {
            #pragma unroll
            for (int w = 0; w < 8; ++w) {
                int j = w*16 + jj;
                st[w].x = ws[OFF_MR + j*128 + k0 + kk];
                st[w].y = ws[OFF_MI + j*128 + k0 + kk];
            }
        } else {
            #pragma unroll
            for (int w = 0; w < 8; ++w) {
                int j = w*16 + jj;
                st[w] = Uv2[j*128 + k0 + kk];
            }
        }
    };
    auto writeU = [&]() {
        float* Ur  = Bbuf;
        float* Ui_ = Bbuf + 2112;
        #pragma unroll
        for (int w = 0; w < 8; ++w) {
            int j = w*16 + jj;
            Ur [kk*132 + j] = st[w].x;
            Ui_[kk*132 + j] = st[w].y;
        }
    };

    gloadU(0);
    // Y-strip -> At (as Yt[c][rg]); At reads all done (post-loop barrier)
    #pragma unroll
    for (int k = 0; k < 4; ++k)
        *(float4*)&At[((cg<<2)+k)*32 + (rg<<2)] =
            make_float4(accr[0][k], acci[0][k], accr[1][k], acci[1][k]);
    #pragma unroll
    for (int r = 0; r < 2; ++r)
        #pragma unroll
        for (int k = 0; k < 4; ++k) { accr[r][k] = 0.f; acci[r][k] = 0.f; }
    writeU();
    __syncthreads();

    // ================= Phase 2 =================
    for (int t = 0; t < 8; ++t) {
        if (t < 7) gloadU(t+1);
        const float* Ur  = Bbuf;
        const float* Ui_ = Bbuf + 2112;
        #pragma unroll
        for (int k2 = 0; k2 < 16; ++k2) {
            const int k = (t<<4) + k2;
            const float4 a4  = *(const float4*)&At[k*32 + (rg<<2)];      // yr0 yi0 yr1 yi1
            const float4 brv = *(const float4*)&Ur [k2*132 + (cg<<2)];
            const float4 biv = *(const float4*)&Ui_[k2*132 + (cg<<2)];
            const float br_[4] = {brv.x, brv.y, brv.z, brv.w};
            const float bi_[4] = {biv.x, biv.y, biv.z, biv.w};
            #pragma unroll
            for (int k = 0; k < 4; ++k) {
                accr[0][k] += a4.x*br_[k] + a4.y*bi_[k];
                acci[0][k] += a4.y*br_[k] - a4.x*bi_[k];
                accr[1][k] += a4.z*br_[k] + a4.w*bi_[k];
                acci[1][k] += a4.w*br_[k] - a4.z*bi_[k];
            }
        }
        __syncthreads();                  // reads of buf done
        if (t < 7) { writeU(); __syncthreads(); }
    }

    // ================= Epilogue =================
    if (m < 32) {
        // store Z^T into Zs: LDS transpose (T in Bbuf region; safe post-barrier)
        float* T_r = Bbuf;               // [16][132]
        float* T_i = Bbuf + 2112;
        #pragma unroll
        for (int r = 0; r < 2; ++r)
            #pragma unroll
            for (int k = 0; k < 4; ++k) {
                T_r[((rg<<1)+r)*132 + (cg<<2)+k] = accr[r][k];
                T_i[((rg<<1)+r)*132 + (cg<<2)+k] = acci[r][k];
            }
        __syncthreads();
        float* dstR = ws + OFF_ZSR + m*MAT;
        float* dstI = ws + OFF_ZSI + m*MAT;
        #pragma unroll
        for (int w = 0; w < 8; ++w) {
            int o  = w*256 + tid;        // 0..2047
            int c  = o >> 4;             // col j 0..127
            int ii = o & 15;             // row-in-strip
            dstR[c*128 + i0 + ii] = T_r[ii*132 + c];
            dstI[c*128 + i0 + ii] = T_i[ii*132 + c];
        }
    } else {
        float* dstR = ws + OFF_VR + (m-32)*MAT;
        float* dstI = ws + OFF_VI + (m-32)*MAT;
        #pragma unroll
        for (int r = 0; r < 2; ++r) {
            float4 vR = make_float4(accr[r][0], accr[r][1], accr[r][2], accr[r][3]);
            float4 vI = make_float4(acci[r][0], acci[r][1], acci[r][2], acci[r][3]);
            *(float4*)&dstR[(i0 + (rg<<1) + r)*128 + (cg<<2)] = vR;
            *(float4*)&dstI[(i0 + (rg<<1) + r)*128 + (cg<<2)] = vI;
        }
    }
}

// ---------------- Kernel 3: tr[q,kk,b] = sum X_qb .* Zs_kkb (complex) ----------------
__global__ __launch_bounds__(256) void k_trace(const float* __restrict__ xr,
                                               const float* __restrict__ xi,
                                               float* __restrict__ ws) {
    const int q = blockIdx.x >> 4, b = blockIdx.x & 15;
    const int tid = threadIdx.x;
    const float4* Xr4  = (const float4*)(xr + (q*16 + b)*MAT);
    const float4* Xi4  = (const float4*)(xi + (q*16 + b)*MAT);
    const float4* Z0r4 = (const float4*)(ws + OFF_ZSR + b*MAT);
    const float4* Z0i4 = (const float4*)(ws + OFF_ZSI + b*MAT);
    const float4* Z1r4 = (const float4*)(ws + OFF_ZSR + (16+b)*MAT);
    const float4* Z1i4 = (const float4*)(ws + OFF_ZSI + (16+b)*MAT);
    float r0 = 0.f, s0 = 0.f, r1 = 0.f, s1 = 0.f;
    #pragma unroll 4
    for (int w = 0; w < 16; ++w) {
        int e = w*256 + tid;
        float4 xrv = Xr4[e], xiv = Xi4[e];
        float4 z0r = Z0r4[e], z0i = Z0i4[e];
        float4 z1r = Z1r4[e], z1i = Z1i4[e];
        r0 += dot4(xrv, z0r) - dot4(xiv, z0i);
        s0 += dot4(xrv, z0i) + dot4(xiv, z0r);
        r1 += dot4(xrv, z1r) - dot4(xiv, z1i);
        s1 += dot4(xrv, z1i) + dot4(xiv, z1r);
    }
    #pragma unroll
    for (int off = 32; off > 0; off >>= 1) {
        r0 += __shfl_down(r0, off);
        s0 += __shfl_down(s0, off);
        r1 += __shfl_down(r1, off);
        s1 += __shfl_down(s1, off);
    }
    __shared__ float red[4][4];
    if ((tid & 63) == 0) {
        int wv = tid >> 6;
        red[wv][0] = r0; red[wv][1] = s0; red[wv][2] = r1; red[wv][3] = s1;
    }
    __syncthreads();
    if (tid == 0) {
        float a0 = red[0][0]+red[1][0]+red[2][0]+red[3][0];
        float a1 = red[0][1]+red[1][1]+red[2][1]+red[3][1];
        float a2 = red[0][2]+red[1][2]+red[2][2]+red[3][2];
        float a3 = red[0][3]+red[1][3]+red[2][3]+red[3][3];
        float* trp = ws + OFF_TR;
        trp[((q*2+0)*16 + b)*2 + 0] = a0;
        trp[((q*2+0)*16 + b)*2 + 1] = a1;
        trp[((q*2+1)*16 + b)*2 + 0] = a2;
        trp[((q*2+1)*16 + b)*2 + 1] = a3;
    }
}

// ---------------- Kernel 4: softmax over b for (q,kk) ----------------
__global__ __launch_bounds__(64) void k_softmax(float* __restrict__ ws) {
    const int t = threadIdx.x;      // 0..63 -> (q,kk)
    const float* trp = ws + OFF_TR + t*32;   // 16 b * 2
    float d[16];
    float mx = -1e30f;
    #pragma unroll
    for (int b = 0; b < 16; ++b) {
        float rr = trp[b*2+0], ii = trp[b*2+1];
        d[b] = sqrtf(rr*rr + ii*ii);
        mx = fmaxf(mx, d[b]);
    }
    float sum = 0.f;
    #pragma unroll
    for (int b = 0; b < 16; ++b) { d[b] = expf(d[b] - mx); sum += d[b]; }
    float inv = 1.f / sum;
    #pragma unroll
    for (int b = 0; b < 16; ++b) ws[OFF_S + t*16 + b] = d[b] * inv;
}

// ---------------- Kernel 5: broadcast output ----------------
__global__ __launch_bounds__(256) void k_out(const float* __restrict__ ws,
                                             float* __restrict__ out) {
    const int t = blockIdx.x >> 4, b = blockIdx.x & 15;
    const float s0 = ws[OFF_S + (t*2+0)*16 + b];
    const float s1 = ws[OFF_S + (t*2+1)*16 + b];
    const float4* Vr0 = (const float4*)(ws + OFF_VR + b*MAT);
    const float4* Vi0 = (const float4*)(ws + OFF_VI + b*MAT);
    const float4* Vr1 = (const float4*)(ws + OFF_VR + (16+b)*MAT);
    const float4* Vi1 = (const float4*)(ws + OFF_VI + (16+b)*MAT);
    float4* outR = (float4*)out + (t*16 + b)*4096;
    float4* outI = (float4*)out + 2097152 + (t*16 + b)*4096;
    #pragma unroll 4
    for (int w = 0; w < 16; ++w) {
        int e = w*256 + threadIdx.x;
        float4 a = Vr0[e], bb = Vi0[e], c = Vr1[e], dd = Vi1[e];
        outR[e] = make_float4(a.x*s0 + bb.x*s1, a.y*s0 + bb.y*s1,
                              a.z*s0 + bb.z*s1, a.w*s0 + bb.w*s1);
        outI[e] = make_float4(c.x*s0 + dd.x*s1, c.y*s0 + dd.y*s1,
                              c.z*s0 + dd.z*s1, c.w*s0 + dd.w*s1);
    }
}

extern "C" void kernel_launch(void* const* d_in, const int* in_sizes, int n_in,
                              void* d_out, int out_size, void* d_ws, size_t ws_size,
                              hipStream_t stream) {
    const float* xr = (const float*)d_in[0];
    const float* xi = (const float*)d_in[1];
    const float* Uq = (const float*)d_in[2];
    const float* Uk = (const float*)d_in[3];
    const float* Uv = (const float*)d_in[4];
    float* ws  = (float*)d_ws;
    float* out = (float*)d_out;

    k_M<<<128, 128, 0, stream>>>(Uq, Uk, ws);
    k_fused<<<512, 256, 0, stream>>>(xr, xi, Uv, ws);
    k_trace<<<512, 256, 0, stream>>>(xr, xi, ws);
    k_softmax<<<1, 64, 0, stream>>>(ws);
    k_out<<<512, 256, 0, stream>>>(ws, out);
}

// Round 7
// 99.258 us; speedup vs baseline: 4.1677x; 4.1677x over previous
//
#include <hip/hip_runtime.h>
#include <math.h>

// Problem constants
#define MAT 16384            // D*D
// Workspace float offsets
#define OFF_MR   0
#define OFF_MI   16384
#define OFF_MTR  32768                    // M^T re
#define OFF_MTI  49152                    // M^T im
#define OFF_UVTR 65536                    // Uv^T re
#define OFF_UVTI 81920                    // Uv^T im
#define OFF_ZSR  2129920                  // Zs = Z^T, [kk*16+b][j][i]
#define OFF_ZSI  (OFF_ZSR + 32*16384)
#define OFF_VR   (OFF_ZSI + 32*16384)     // V natural [t*16+b][i][j]
#define OFF_VI   (OFF_VR + 32*16384)
#define OFF_TR   (OFF_VI + 32*16384)      // tr[q][kk][b][2]
#define OFF_S    (OFF_TR + 2048)          // s[q][kk][b]

__device__ __forceinline__ float dot4(float4 a, float4 b) {
    return a.x*b.x + a.y*b.y + a.z*b.z + a.w*b.w;
}

// ---------------- Kernel 1: M = Uq^H * Uk, plus M^T and Uv^T planes ----------------
__global__ __launch_bounds__(128) void k_M(const float* __restrict__ Uq,
                                           const float* __restrict__ Uk,
                                           const float* __restrict__ Uv,
                                           float* __restrict__ ws) {
    const int i = blockIdx.x;
    const int j = threadIdx.x;
    __shared__ float qr_s[128], qi_s[128];
    qr_s[j] = Uq[(j*128 + i)*2 + 0];   // Uq[p=j, i]
    qi_s[j] = Uq[(j*128 + i)*2 + 1];
    __syncthreads();
    const float2* Uk2 = (const float2*)Uk;
    float mr = 0.f, mi = 0.f;
    #pragma unroll 8
    for (int p = 0; p < 128; ++p) {
        float2 k2 = Uk2[p*128 + j];
        float qr = qr_s[p], qi = qi_s[p];
        mr += qr*k2.x + qi*k2.y;       // conj(Uq[p,i]) * Uk[p,j]
        mi += qr*k2.y - qi*k2.x;
    }
    ws[OFF_MR  + i*128 + j] = mr;
    ws[OFF_MI  + i*128 + j] = mi;
    ws[OFF_MTR + j*128 + i] = mr;      // transposed planes (scattered, tiny)
    ws[OFF_MTI + j*128 + i] = mi;
    float2 uv = ((const float2*)Uv)[i*128 + j];
    ws[OFF_UVTR + j*128 + i] = uv.x;
    ws[OFF_UVTI + j*128 + i] = uv.y;
}

// ---------------- Kernel 2: fused two-sided evolve Z = U X U^H (v3) ----------------
// grid 1024: m = bid&63 (XCD = m%8 shared by all strips of m and its V twin),
//            strip i0 = (bid>>6)*8. 256 threads -> 4 blocks/CU co-resident.
// Thread tile 2 rows x 2 cols: rp = tid&3 (row pair), cg = tid>>2 (col pair).
// LDS 24KB: At (A-strip / Y-strip, interleaved) 8KB + single B buf 16KB.
// B streamed tiles (16 p-rows x 128 cols re+im) reg-prefetched across barrier.
// Phase 1: Y[i,c] = sum_p U[i,p] X[p,c]     (U = M if m<32 else Uv; X = X[m&31])
// Phase 2: Z[i,j] = sum_k Y[i,k] conj(U[j,k]) streaming U^T planes (MT/UvT).
// Epilogue: m<32 -> Z^T to Zs (LDS transpose); m>=32 -> Z natural to V.
__global__ __launch_bounds__(256) void k_fused(const float* __restrict__ xr,
                                               const float* __restrict__ xi,
                                               const float* __restrict__ Uv,
                                               float* __restrict__ ws) {
    const int bid = blockIdx.x;
    const int m   = bid & 63;
    const int i0  = (bid >> 6) * 8;
    const int tid = threadIdx.x;
    const int rp  = tid & 3;             // rows i0 + rp*2 + {0,1}
    const int cg  = tid >> 2;            // cols cg*2 + {0,1}

    __shared__ __align__(16) float smem_f[2048 + 4096];   // 24576 B
    float* At   = smem_f;                // [p][rp][4] = {ar0,ai0,ar1,ai1}
    float* Bbuf = smem_f + 2048;         // [re 2048][im 2048]

    float accr[2][2], acci[2][2];
    #pragma unroll
    for (int r = 0; r < 2; ++r)
        #pragma unroll
        for (int k = 0; k < 2; ++k) { accr[r][k] = 0.f; acci[r][k] = 0.f; }

    const float2* Uv2 = (const float2*)Uv;
    const float4* Xr4 = (const float4*)(xr + (m & 31)*MAT);
    const float4* Xi4 = (const float4*)(xi + (m & 31)*MAT);
    const float4* P2r = (const float4*)(ws + (m < 32 ? OFF_MTR : OFF_UVTR));
    const float4* P2i = (const float4*)(ws + (m < 32 ? OFF_MTI : OFF_UVTI));

    // ---- A-strip: U rows i0..i0+7, all p, interleaved ----
    #pragma unroll
    for (int w = 0; w < 2; ++w) {
        int slot = w*256 + tid;          // 0..511
        int rs = slot & 3;
        int p  = slot >> 2;              // 0..127
        float ar0, ai0, ar1, ai1;
        if (m < 32) {
            ar0 = ws[OFF_MR + (i0 + rs*2    )*128 + p];
            ai0 = ws[OFF_MI + (i0 + rs*2    )*128 + p];
            ar1 = ws[OFF_MR + (i0 + rs*2 + 1)*128 + p];
            ai1 = ws[OFF_MI + (i0 + rs*2 + 1)*128 + p];
        } else {
            float2 u0 = Uv2[(i0 + rs*2    )*128 + p];
            float2 u1 = Uv2[(i0 + rs*2 + 1)*128 + p];
            ar0 = u0.x; ai0 = u0.y; ar1 = u1.x; ai1 = u1.y;
        }
        *(float4*)&At[p*16 + rs*4] = make_float4(ar0, ai0, ar1, ai1);
    }

    // ---- streamed-B staging: tile t = 16 rows x 128 cols re+im ----
    float4 pr0, pr1, pi0, pi1;
    auto gload = [&](const float4* R, const float4* I, int t) {
        int b0 = t*512;
        pr0 = R[b0 + tid];
        pr1 = R[b0 + 256 + tid];
        pi0 = I[b0 + tid];
        pi1 = I[b0 + 256 + tid];
    };
    auto writeB = [&]() {
        ((float4*)Bbuf)[tid]                = pr0;
        ((float4*)Bbuf)[tid + 256]          = pr1;
        ((float4*)(Bbuf + 2048))[tid]       = pi0;
        ((float4*)(Bbuf + 2048))[tid + 256] = pi1;
    };

    // ================= Phase 1: Y = U * X =================
    gload(Xr4, Xi4, 0); writeB(); __syncthreads();
    for (int t = 0; t < 8; ++t) {
        if (t < 7) gload(Xr4, Xi4, t+1);
        #pragma unroll
        for (int pp = 0; pp < 16; ++pp) {
            int p = (t<<4) + pp;
            float4 a4  = *(const float4*)&At[p*16 + (rp<<2)];
            float2 brv = *(const float2*)&Bbuf[pp*128 + (cg<<1)];
            float2 biv = *(const float2*)&Bbuf[2048 + pp*128 + (cg<<1)];
            accr[0][0] += a4.x*brv.x - a4.y*biv.x;
            acci[0][0] += a4.x*biv.x + a4.y*brv.x;
            accr[0][1] += a4.x*brv.y - a4.y*biv.y;
            acci[0][1] += a4.x*biv.y + a4.y*brv.y;
            accr[1][0] += a4.z*brv.x - a4.w*biv.x;
            acci[1][0] += a4.z*biv.x + a4.w*brv.x;
            accr[1][1] += a4.z*brv.y - a4.w*biv.y;
            acci[1][1] += a4.z*biv.y + a4.w*brv.y;
        }
        __syncthreads();
        if (t < 7) { writeB(); __syncthreads(); }
    }

    // ================= Interlude: Y-strip -> At as Yt[c][rp] =================
    gload(P2r, P2i, 0);                  // prefetch phase-2 tile 0
    #pragma unroll
    for (int k = 0; k < 2; ++k)
        *(float4*)&At[((cg<<1)+k)*16 + (rp<<2)] =
            make_float4(accr[0][k], acci[0][k], accr[1][k], acci[1][k]);
    #pragma unroll
    for (int r = 0; r < 2; ++r)
        #pragma unroll
        for (int k = 0; k < 2; ++k) { accr[r][k] = 0.f; acci[r][k] = 0.f; }
    writeB();
    __syncthreads();

    // ================= Phase 2: Z = Y * U^H =================
    for (int t = 0; t < 8; ++t) {
        if (t < 7) gload(P2r, P2i, t+1);
        #pragma unroll
        for (int k2 = 0; k2 < 16; ++k2) {
            int k = (t<<4) + k2;
            float4 a4  = *(const float4*)&At[k*16 + (rp<<2)];    // yr0 yi0 yr1 yi1
            float2 urv = *(const float2*)&Bbuf[k2*128 + (cg<<1)];
            float2 uiv = *(const float2*)&Bbuf[2048 + k2*128 + (cg<<1)];
            accr[0][0] += a4.x*urv.x + a4.y*uiv.x;
            acci[0][0] += a4.y*urv.x - a4.x*uiv.x;
            accr[0][1] += a4.x*urv.y + a4.y*uiv.y;
            acci[0][1] += a4.y*urv.y - a4.x*uiv.y;
            accr[1][0] += a4.z*urv.x + a4.w*uiv.x;
            acci[1][0] += a4.w*urv.x - a4.z*uiv.x;
            accr[1][1] += a4.z*urv.y + a4.w*uiv.y;
            acci[1][1] += a4.w*urv.y - a4.z*uiv.y;
        }
        __syncthreads();
        if (t < 7) { writeB(); __syncthreads(); }
    }

    // ================= Epilogue =================
    if (m < 32) {
        float* T_r = Bbuf;               // [8][132]
        float* T_i = Bbuf + 1056;
        #pragma unroll
        for (int r = 0; r < 2; ++r)
            #pragma unroll
            for (int k = 0; k < 2; ++k) {
                T_r[((rp<<1)+r)*132 + (cg<<1)+k] = accr[r][k];
                T_i[((rp<<1)+r)*132 + (cg<<1)+k] = acci[r][k];
            }
        __syncthreads();
        float* dstR = ws + OFF_ZSR + m*MAT;
        float* dstI = ws + OFF_ZSI + m*MAT;
        #pragma unroll
        for (int w = 0; w < 4; ++w) {
            int o  = w*256 + tid;        // 0..1023
            int c  = o >> 3;             // col j 0..127
            int ii = o & 7;              // row-in-strip
            dstR[c*128 + i0 + ii] = T_r[ii*132 + c];
            dstI[c*128 + i0 + ii] = T_i[ii*132 + c];
        }
    } else {
        float* dstR = ws + OFF_VR + (m-32)*MAT;
        float* dstI = ws + OFF_VI + (m-32)*MAT;
        #pragma unroll
        for (int r = 0; r < 2; ++r) {
            *(float2*)&dstR[(i0 + (rp<<1) + r)*128 + (cg<<1)] =
                make_float2(accr[r][0], accr[r][1]);
            *(float2*)&dstI[(i0 + (rp<<1) + r)*128 + (cg<<1)] =
                make_float2(acci[r][0], acci[r][1]);
        }
    }
}

// ---------------- Kernel 3: tr[q,kk,b] = sum X_qb .* Zs_kkb (complex) ----------------
__global__ __launch_bounds__(256) void k_trace(const float* __restrict__ xr,
                                               const float* __restrict__ xi,
                                               float* __restrict__ ws) {
    const int q = blockIdx.x >> 4, b = blockIdx.x & 15;
    const int tid = threadIdx.x;
    const float4* Xr4  = (const float4*)(xr + (q*16 + b)*MAT);
    const float4* Xi4  = (const float4*)(xi + (q*16 + b)*MAT);
    const float4* Z0r4 = (const float4*)(ws + OFF_ZSR + b*MAT);
    const float4* Z0i4 = (const float4*)(ws + OFF_ZSI + b*MAT);
    const float4* Z1r4 = (const float4*)(ws + OFF_ZSR + (16+b)*MAT);
    const float4* Z1i4 = (const float4*)(ws + OFF_ZSI + (16+b)*MAT);
    float r0 = 0.f, s0 = 0.f, r1 = 0.f, s1 = 0.f;
    #pragma unroll 4
    for (int w = 0; w < 16; ++w) {
        int e = w*256 + tid;
        float4 xrv = Xr4[e], xiv = Xi4[e];
        float4 z0r = Z0r4[e], z0i = Z0i4[e];
        float4 z1r = Z1r4[e], z1i = Z1i4[e];
        r0 += dot4(xrv, z0r) - dot4(xiv, z0i);
        s0 += dot4(xrv, z0i) + dot4(xiv, z0r);
        r1 += dot4(xrv, z1r) - dot4(xiv, z1i);
        s1 += dot4(xrv, z1i) + dot4(xiv, z1r);
    }
    #pragma unroll
    for (int off = 32; off > 0; off >>= 1) {
        r0 += __shfl_down(r0, off);
        s0 += __shfl_down(s0, off);
        r1 += __shfl_down(r1, off);
        s1 += __shfl_down(s1, off);
    }
    __shared__ float red[4][4];
    if ((tid & 63) == 0) {
        int wv = tid >> 6;
        red[wv][0] = r0; red[wv][1] = s0; red[wv][2] = r1; red[wv][3] = s1;
    }
    __syncthreads();
    if (tid == 0) {
        float a0 = red[0][0]+red[1][0]+red[2][0]+red[3][0];
        float a1 = red[0][1]+red[1][1]+red[2][1]+red[3][1];
        float a2 = red[0][2]+red[1][2]+red[2][2]+red[3][2];
        float a3 = red[0][3]+red[1][3]+red[2][3]+red[3][3];
        float* trp = ws + OFF_TR;
        trp[((q*2+0)*16 + b)*2 + 0] = a0;
        trp[((q*2+0)*16 + b)*2 + 1] = a1;
        trp[((q*2+1)*16 + b)*2 + 0] = a2;
        trp[((q*2+1)*16 + b)*2 + 1] = a3;
    }
}

// ---------------- Kernel 4: softmax over b for (q,kk) ----------------
__global__ __launch_bounds__(64) void k_softmax(float* __restrict__ ws) {
    const int t = threadIdx.x;      // 0..63 -> (q,kk)
    const float* trp = ws + OFF_TR + t*32;   // 16 b * 2
    float d[16];
    float mx = -1e30f;
    #pragma unroll
    for (int b = 0; b < 16; ++b) {
        float rr = trp[b*2+0], ii = trp[b*2+1];
        d[b] = sqrtf(rr*rr + ii*ii);
        mx = fmaxf(mx, d[b]);
    }
    float sum = 0.f;
    #pragma unroll
    for (int b = 0; b < 16; ++b) { d[b] = expf(d[b] - mx); sum += d[b]; }
    float inv = 1.f / sum;
    #pragma unroll
    for (int b = 0; b < 16; ++b) ws[OFF_S + t*16 + b] = d[b] * inv;
}

// ---------------- Kernel 5: broadcast output ----------------
__global__ __launch_bounds__(256) void k_out(const float* __restrict__ ws,
                                             float* __restrict__ out) {
    const int t = blockIdx.x >> 4, b = blockIdx.x & 15;
    const float s0 = ws[OFF_S + (t*2+0)*16 + b];
    const float s1 = ws[OFF_S + (t*2+1)*16 + b];
    const float4* Vr0 = (const float4*)(ws + OFF_VR + b*MAT);
    const float4* Vi0 = (const float4*)(ws + OFF_VI + b*MAT);
    const float4* Vr1 = (const float4*)(ws + OFF_VR + (16+b)*MAT);
    const float4* Vi1 = (const float4*)(ws + OFF_VI + (16+b)*MAT);
    float4* outR = (float4*)out + (t*16 + b)*4096;
    float4* outI = (float4*)out + 2097152 + (t*16 + b)*4096;
    #pragma unroll 4
    for (int w = 0; w < 16; ++w) {
        int e = w*256 + threadIdx.x;
        float4 a = Vr0[e], bb = Vi0[e], c = Vr1[e], dd = Vi1[e];
        outR[e] = make_float4(a.x*s0 + bb.x*s1, a.y*s0 + bb.y*s1,
                              a.z*s0 + bb.z*s1, a.w*s0 + bb.w*s1);
        outI[e] = make_float4(c.x*s0 + dd.x*s1, c.y*s0 + dd.y*s1,
                              c.z*s0 + dd.z*s1, c.w*s0 + dd.w*s1);
    }
}

extern "C" void kernel_launch(void* const* d_in, const int* in_sizes, int n_in,
                              void* d_out, int out_size, void* d_ws, size_t ws_size,
                              hipStream_t stream) {
    const float* xr = (const float*)d_in[0];
    const float* xi = (const float*)d_in[1];
    const float* Uq = (const float*)d_in[2];
    const float* Uk = (const float*)d_in[3];
    const float* Uv = (const float*)d_in[4];
    float* ws  = (float*)d_ws;
    float* out = (float*)d_out;

    k_M<<<128, 128, 0, stream>>>(Uq, Uk, Uv, ws);
    k_fused<<<1024, 256, 0, stream>>>(xr, xi, Uv, ws);
    k_trace<<<512, 256, 0, stream>>>(xr, xi, ws);
    k_softmax<<<1, 64, 0, stream>>>(ws);
    k_out<<<512, 256, 0, stream>>>(ws, out);
}

// Round 8
// 92.519 us; speedup vs baseline: 4.4713x; 1.0728x over previous
//
#include <hip/hip_runtime.h>
#include <math.h>

// Problem constants
#define MAT 16384            // D*D
// Workspace float offsets
#define OFF_MR   0
#define OFF_MI   16384
#define OFF_MTR  32768                    // M^T re
#define OFF_MTI  49152                    // M^T im
#define OFF_UVTR 65536                    // Uv^T re
#define OFF_UVTI 81920                    // Uv^T im
#define OFF_ZSR  2129920                  // Zs = Z^T, [kk*16+b][j][i]
#define OFF_ZSI  (OFF_ZSR + 32*16384)
#define OFF_VR   (OFF_ZSI + 32*16384)     // V natural [t*16+b][i][j]
#define OFF_VI   (OFF_VR + 32*16384)
#define OFF_TR   (OFF_VI + 32*16384)      // tr[q][kk][b][2]
#define OFF_S    (OFF_TR + 2048)          // s[q][kk][b]

__device__ __forceinline__ float dot4(float4 a, float4 b) {
    return a.x*b.x + a.y*b.y + a.z*b.z + a.w*b.w;
}

// ---------------- Kernel 1: M = Uq^H * Uk, plus M^T and Uv^T planes ----------------
__global__ __launch_bounds__(128) void k_M(const float* __restrict__ Uq,
                                           const float* __restrict__ Uk,
                                           const float* __restrict__ Uv,
                                           float* __restrict__ ws) {
    const int i = blockIdx.x;
    const int j = threadIdx.x;
    __shared__ float qr_s[128], qi_s[128];
    qr_s[j] = Uq[(j*128 + i)*2 + 0];   // Uq[p=j, i]
    qi_s[j] = Uq[(j*128 + i)*2 + 1];
    __syncthreads();
    const float2* Uk2 = (const float2*)Uk;
    float mr = 0.f, mi = 0.f;
    #pragma unroll 8
    for (int p = 0; p < 128; ++p) {
        float2 k2 = Uk2[p*128 + j];
        float qr = qr_s[p], qi = qi_s[p];
        mr += qr*k2.x + qi*k2.y;       // conj(Uq[p,i]) * Uk[p,j]
        mi += qr*k2.y - qi*k2.x;
    }
    ws[OFF_MR  + i*128 + j] = mr;
    ws[OFF_MI  + i*128 + j] = mi;
    ws[OFF_MTR + j*128 + i] = mr;      // transposed planes (scattered, tiny)
    ws[OFF_MTI + j*128 + i] = mi;
    float2 uv = ((const float2*)Uv)[i*128 + j];
    ws[OFF_UVTR + j*128 + i] = uv.x;
    ws[OFF_UVTI + j*128 + i] = uv.y;
}

// ---------------- Kernel 2: fused two-sided evolve Z = U X U^H (v4) ----------------
// grid 1024: m = bid&63 (XCD = m%8 shared by all strips of m and its V twin),
//            strip i0 = (bid>>6)*8. 256 threads = 4 waves, 4 blocks/CU (40KB LDS).
// WAVE-PRIVATE B slices: wave wv owns output cols [wv*32, wv*32+32). Its B tile
// slice (16 p-rows x 32 cols, re+im, 4KB) is double-buffered in private LDS with
// per-wave vmcnt/lgkmcnt ordering -> ZERO __syncthreads in the main loops.
// Lane: rp = lane&3 (row pair of 8-row strip), cp = lane>>2 (col pair in slice).
// Phase 1: Y[i,c] = sum_p U[i,p] X[p,c]     (U = M if m<32 else Uv; X = X[m&31])
// Phase 2: Z[i,j] = sum_k Y[i,k] conj(U[j,k]), slices stream U^T planes (MT/UvT).
// Barriers only: after At load, around interlude Yt exchange, around Z^T epilogue.
__global__ __launch_bounds__(256) void k_fused(const float* __restrict__ xr,
                                               const float* __restrict__ xi,
                                               const float* __restrict__ Uv,
                                               float* __restrict__ ws) {
    const int bid  = blockIdx.x;
    const int m    = bid & 63;
    const int i0   = (bid >> 6) * 8;
    const int tid  = threadIdx.x;
    const int wv   = tid >> 6;
    const int lane = tid & 63;
    const int rp   = lane & 3;           // rows i0 + rp*2 + {0,1}
    const int cp   = lane >> 2;          // 0..15: cols wv*32 + cp*2 + {0,1}
    const int j8   = lane & 7;           // staging col f4-chunk
    const int rr   = lane >> 3;          // staging row 0..7

    // LDS: At (A-strip / Y) 2048 f | 4 waves x (dbuf 2 x [re 512 | im 512]) = 40960 B
    __shared__ __align__(16) float smem[2048 + 4*2048];
    float* At = smem;                    // [p][rp][4] = {r0,i0,r1,i1}
    float* Sl = smem + 2048 + wv*2048;   // this wave's slice dbuf

    float accr[2][2], acci[2][2];
    #pragma unroll
    for (int r = 0; r < 2; ++r)
        #pragma unroll
        for (int k = 0; k < 2; ++k) { accr[r][k] = 0.f; acci[r][k] = 0.f; }

    const float2* Uv2 = (const float2*)Uv;
    const float4* B1r = (const float4*)(xr + (m & 31)*MAT);
    const float4* B1i = (const float4*)(xi + (m & 31)*MAT);
    const float4* B2r = (const float4*)(ws + (m < 32 ? OFF_MTR : OFF_UVTR));
    const float4* B2i = (const float4*)(ws + (m < 32 ? OFF_MTI : OFF_UVTI));

    // ---- A-strip: U rows i0..i0+7, all p, interleaved (cooperative) ----
    #pragma unroll
    for (int w = 0; w < 2; ++w) {
        int slot = w*256 + tid;          // 0..511
        int rs = slot & 3;
        int p  = slot >> 2;              // 0..127
        float ar0, ai0, ar1, ai1;
        if (m < 32) {
            ar0 = ws[OFF_MR + (i0 + rs*2    )*128 + p];
            ai0 = ws[OFF_MI + (i0 + rs*2    )*128 + p];
            ar1 = ws[OFF_MR + (i0 + rs*2 + 1)*128 + p];
            ai1 = ws[OFF_MI + (i0 + rs*2 + 1)*128 + p];
        } else {
            float2 u0 = Uv2[(i0 + rs*2    )*128 + p];
            float2 u1 = Uv2[(i0 + rs*2 + 1)*128 + p];
            ar0 = u0.x; ai0 = u0.y; ar1 = u1.x; ai1 = u1.y;
        }
        *(float4*)&At[p*16 + rs*4] = make_float4(ar0, ai0, ar1, ai1);
    }
    __syncthreads();

    // ---- wave-private slice staging ----
    float4 qr0, qr1, qi0, qi1;
    auto gload = [&](const float4* R, const float4* I, int t) {
        int base = (t*16 + rr)*32 + wv*8 + j8;
        qr0 = R[base];       qr1 = R[base + 256];
        qi0 = I[base];       qi1 = I[base + 256];
    };
    auto swrite = [&](int h) {
        float* d = Sl + h*1024;
        *(float4*)&d[rr*32 + (j8<<2)]           = qr0;
        *(float4*)&d[(rr+8)*32 + (j8<<2)]       = qr1;
        *(float4*)&d[512 + rr*32 + (j8<<2)]     = qi0;
        *(float4*)&d[512 + (rr+8)*32 + (j8<<2)] = qi1;
    };

    // ================= Phase 1: Y = U * X  (no barriers) =================
    gload(B1r, B1i, 0); swrite(0); gload(B1r, B1i, 1);
    for (int t = 0; t < 8; ++t) {
        const int h = t & 1;
        const float* sr = Sl + h*1024;
        const float* si = sr + 512;
        #pragma unroll
        for (int pp = 0; pp < 16; ++pp) {
            float4 a4 = *(const float4*)&At[((t<<4)+pp)*16 + (rp<<2)];
            float2 br = *(const float2*)&sr[pp*32 + (cp<<1)];
            float2 bi = *(const float2*)&si[pp*32 + (cp<<1)];
            accr[0][0] += a4.x*br.x - a4.y*bi.x;
            acci[0][0] += a4.x*bi.x + a4.y*br.x;
            accr[0][1] += a4.x*br.y - a4.y*bi.y;
            acci[0][1] += a4.x*bi.y + a4.y*br.y;
            accr[1][0] += a4.z*br.x - a4.w*bi.x;
            acci[1][0] += a4.z*bi.x + a4.w*br.x;
            accr[1][1] += a4.z*br.y - a4.w*bi.y;
            acci[1][1] += a4.z*bi.y + a4.w*br.y;
        }
        if (t < 7) { swrite((t+1)&1); if (t < 6) gload(B1r, B1i, t+2); }
    }

    // ================= Interlude: exchange Y via At =================
    gload(B2r, B2i, 0);                  // prefetch phase-2 tile 0 (hides sync)
    __syncthreads();                     // all phase-1 At reads done
    *(float4*)&At[(wv*32 + (cp<<1)    )*16 + (rp<<2)] =
        make_float4(accr[0][0], acci[0][0], accr[1][0], acci[1][0]);
    *(float4*)&At[(wv*32 + (cp<<1) + 1)*16 + (rp<<2)] =
        make_float4(accr[0][1], acci[0][1], accr[1][1], acci[1][1]);
    #pragma unroll
    for (int r = 0; r < 2; ++r)
        #pragma unroll
        for (int k = 0; k < 2; ++k) { accr[r][k] = 0.f; acci[r][k] = 0.f; }
    __syncthreads();                     // Yt visible to all waves

    // ================= Phase 2: Z = Y * U^H  (no barriers) =================
    swrite(0); gload(B2r, B2i, 1);
    for (int t = 0; t < 8; ++t) {
        const int h = t & 1;
        const float* sr = Sl + h*1024;
        const float* si = sr + 512;
        #pragma unroll
        for (int k2 = 0; k2 < 16; ++k2) {
            float4 a4 = *(const float4*)&At[((t<<4)+k2)*16 + (rp<<2)]; // yr0 yi0 yr1 yi1
            float2 ur = *(const float2*)&sr[k2*32 + (cp<<1)];
            float2 ui = *(const float2*)&si[k2*32 + (cp<<1)];
            accr[0][0] += a4.x*ur.x + a4.y*ui.x;
            acci[0][0] += a4.y*ur.x - a4.x*ui.x;
            accr[0][1] += a4.x*ur.y + a4.y*ui.y;
            acci[0][1] += a4.y*ur.y - a4.x*ui.y;
            accr[1][0] += a4.z*ur.x + a4.w*ui.x;
            acci[1][0] += a4.w*ur.x - a4.z*ui.x;
            accr[1][1] += a4.z*ur.y + a4.w*ui.y;
            acci[1][1] += a4.w*ur.y - a4.z*ui.y;
        }
        if (t < 7) { swrite((t+1)&1); if (t < 6) gload(B2r, B2i, t+2); }
    }

    // ================= Epilogue =================
    if (m < 32) {
        __syncthreads();                 // slices dead, reuse for transpose
        float* T_r = smem + 2048;        // [8][132]
        float* T_i = smem + 2048 + 1056;
        #pragma unroll
        for (int r = 0; r < 2; ++r)
            #pragma unroll
            for (int k = 0; k < 2; ++k) {
                T_r[((rp<<1)+r)*132 + wv*32 + (cp<<1)+k] = accr[r][k];
                T_i[((rp<<1)+r)*132 + wv*32 + (cp<<1)+k] = acci[r][k];
            }
        __syncthreads();
        float* dstR = ws + OFF_ZSR + m*MAT;
        float* dstI = ws + OFF_ZSI + m*MAT;
        #pragma unroll
        for (int w = 0; w < 4; ++w) {
            int o  = w*256 + tid;        // 0..1023
            int c  = o >> 3;             // col j 0..127
            int ii = o & 7;              // row-in-strip
            dstR[c*128 + i0 + ii] = T_r[ii*132 + c];
            dstI[c*128 + i0 + ii] = T_i[ii*132 + c];
        }
    } else {
        float* dstR = ws + OFF_VR + (m-32)*MAT;
        float* dstI = ws + OFF_VI + (m-32)*MAT;
        #pragma unroll
        for (int r = 0; r < 2; ++r) {
            *(float2*)&dstR[(i0 + (rp<<1) + r)*128 + wv*32 + (cp<<1)] =
                make_float2(accr[r][0], accr[r][1]);
            *(float2*)&dstI[(i0 + (rp<<1) + r)*128 + wv*32 + (cp<<1)] =
                make_float2(acci[r][0], acci[r][1]);
        }
    }
}

// ---------------- Kernel 3: tr[q,kk,b] = sum X_qb .* Zs_kkb (complex) ----------------
__global__ __launch_bounds__(256) void k_trace(const float* __restrict__ xr,
                                               const float* __restrict__ xi,
                                               float* __restrict__ ws) {
    const int q = blockIdx.x >> 4, b = blockIdx.x & 15;
    const int tid = threadIdx.x;
    const float4* Xr4  = (const float4*)(xr + (q*16 + b)*MAT);
    const float4* Xi4  = (const float4*)(xi + (q*16 + b)*MAT);
    const float4* Z0r4 = (const float4*)(ws + OFF_ZSR + b*MAT);
    const float4* Z0i4 = (const float4*)(ws + OFF_ZSI + b*MAT);
    const float4* Z1r4 = (const float4*)(ws + OFF_ZSR + (16+b)*MAT);
    const float4* Z1i4 = (const float4*)(ws + OFF_ZSI + (16+b)*MAT);
    float r0 = 0.f, s0 = 0.f, r1 = 0.f, s1 = 0.f;
    #pragma unroll 4
    for (int w = 0; w < 16; ++w) {
        int e = w*256 + tid;
        float4 xrv = Xr4[e], xiv = Xi4[e];
        float4 z0r = Z0r4[e], z0i = Z0i4[e];
        float4 z1r = Z1r4[e], z1i = Z1i4[e];
        r0 += dot4(xrv, z0r) - dot4(xiv, z0i);
        s0 += dot4(xrv, z0i) + dot4(xiv, z0r);
        r1 += dot4(xrv, z1r) - dot4(xiv, z1i);
        s1 += dot4(xrv, z1i) + dot4(xiv, z1r);
    }
    #pragma unroll
    for (int off = 32; off > 0; off >>= 1) {
        r0 += __shfl_down(r0, off);
        s0 += __shfl_down(s0, off);
        r1 += __shfl_down(r1, off);
        s1 += __shfl_down(s1, off);
    }
    __shared__ float red[4][4];
    if ((tid & 63) == 0) {
        int wv = tid >> 6;
        red[wv][0] = r0; red[wv][1] = s0; red[wv][2] = r1; red[wv][3] = s1;
    }
    __syncthreads();
    if (tid == 0) {
        float a0 = red[0][0]+red[1][0]+red[2][0]+red[3][0];
        float a1 = red[0][1]+red[1][1]+red[2][1]+red[3][1];
        float a2 = red[0][2]+red[1][2]+red[2][2]+red[3][2];
        float a3 = red[0][3]+red[1][3]+red[2][3]+red[3][3];
        float* trp = ws + OFF_TR;
        trp[((q*2+0)*16 + b)*2 + 0] = a0;
        trp[((q*2+0)*16 + b)*2 + 1] = a1;
        trp[((q*2+1)*16 + b)*2 + 0] = a2;
        trp[((q*2+1)*16 + b)*2 + 1] = a3;
    }
}

// ---------------- Kernel 4: softmax over b for (q,kk) ----------------
__global__ __launch_bounds__(64) void k_softmax(float* __restrict__ ws) {
    const int t = threadIdx.x;      // 0..63 -> (q,kk)
    const float* trp = ws + OFF_TR + t*32;   // 16 b * 2
    float d[16];
    float mx = -1e30f;
    #pragma unroll
    for (int b = 0; b < 16; ++b) {
        float rr = trp[b*2+0], ii = trp[b*2+1];
        d[b] = sqrtf(rr*rr + ii*ii);
        mx = fmaxf(mx, d[b]);
    }
    float sum = 0.f;
    #pragma unroll
    for (int b = 0; b < 16; ++b) { d[b] = expf(d[b] - mx); sum += d[b]; }
    float inv = 1.f / sum;
    #pragma unroll
    for (int b = 0; b < 16; ++b) ws[OFF_S + t*16 + b] = d[b] * inv;
}

// ---------------- Kernel 5: broadcast output ----------------
__global__ __launch_bounds__(256) void k_out(const float* __restrict__ ws,
                                             float* __restrict__ out) {
    const int t = blockIdx.x >> 4, b = blockIdx.x & 15;
    const float s0 = ws[OFF_S + (t*2+0)*16 + b];
    const float s1 = ws[OFF_S + (t*2+1)*16 + b];
    const float4* Vr0 = (const float4*)(ws + OFF_VR + b*MAT);
    const float4* Vi0 = (const float4*)(ws + OFF_VI + b*MAT);
    const float4* Vr1 = (const float4*)(ws + OFF_VR + (16+b)*MAT);
    const float4* Vi1 = (const float4*)(ws + OFF_VI + (16+b)*MAT);
    float4* outR = (float4*)out + (t*16 + b)*4096;
    float4* outI = (float4*)out + 2097152 + (t*16 + b)*4096;
    #pragma unroll 4
    for (int w = 0; w < 16; ++w) {
        int e = w*256 + threadIdx.x;
        float4 a = Vr0[e], bb = Vi0[e], c = Vr1[e], dd = Vi1[e];
        outR[e] = make_float4(a.x*s0 + bb.x*s1, a.y*s0 + bb.y*s1,
                              a.z*s0 + bb.z*s1, a.w*s0 + bb.w*s1);
        outI[e] = make_float4(c.x*s0 + dd.x*s1, c.y*s0 + dd.y*s1,
                              c.z*s0 + dd.z*s1, c.w*s0 + dd.w*s1);
    }
}

extern "C" void kernel_launch(void* const* d_in, const int* in_sizes, int n_in,
                              void* d_out, int out_size, void* d_ws, size_t ws_size,
                              hipStream_t stream) {
    const float* xr = (const float*)d_in[0];
    const float* xi = (const float*)d_in[1];
    const float* Uq = (const float*)d_in[2];
    const float* Uk = (const float*)d_in[3];
    const float* Uv = (const float*)d_in[4];
    float* ws  = (float*)d_ws;
    float* out = (float*)d_out;

    k_M<<<128, 128, 0, stream>>>(Uq, Uk, Uv, ws);
    k_fused<<<1024, 256, 0, stream>>>(xr, xi, Uv, ws);
    k_trace<<<512, 256, 0, stream>>>(xr, xi, ws);
    k_softmax<<<1, 64, 0, stream>>>(ws);
    k_out<<<512, 256, 0, stream>>>(ws, out);
}